// Round 7
// baseline (734.243 us; speedup 1.0000x reference)
//
#include <hip/hip_runtime.h>
#include <cstdint>
#include <cstddef>

typedef __attribute__((ext_vector_type(8))) short short8;
typedef __attribute__((ext_vector_type(4))) float f32x4;

#define D_MODEL 2048
#define KV_DIM  512
#define N_HEADS 32
#define N_KV    8
#define D_K     64
#define B_SZ    4
#define T_SEQ   2048
#define M_TOT   (B_SZ * T_SEQ)        /* 8192 */
#define N1      (D_MODEL + 2 * KV_DIM) /* 3072 */
#define NEG_BIG (-1e30f)
/* 1/sqrt(64) * log2(e): folded into q at GEMM epilogue so softmax is pure exp2 */
#define Q_PRESCALE 0.18033688011112042f

__device__ __forceinline__ unsigned short f2bf(float f) {
    union { float f; unsigned int i; } c; c.f = f;
    unsigned int u = c.i;
    u += 0x7FFFu + ((u >> 16) & 1u);   // RNE
    return (unsigned short)(u >> 16);
}

// v_cvt_pk_bf16_f32: lo -> bits[15:0], hi -> bits[31:16] (no builtin on gfx950)
__device__ __forceinline__ unsigned int cvtpk_bf16(float lo, float hi) {
    unsigned int r;
    asm("v_cvt_pk_bf16_f32 %0, %1, %2" : "=v"(r) : "v"(lo), "v"(hi));
    return r;
}

// 2^x, single trans op (logits are pre-scaled by log2e)
__device__ __forceinline__ float e2(float x) {
    float r;
    asm("v_exp_f32 %0, %1" : "=v"(r) : "v"(x));
    return r;
}

// async global->LDS, 16B per lane; LDS dest = wave-uniform base + lane*16
__device__ __forceinline__ void async16(unsigned short* lds, const unsigned short* g) {
    __builtin_amdgcn_global_load_lds(
        (const __attribute__((address_space(1))) unsigned int*)g,
        (__attribute__((address_space(3))) unsigned int*)lds, 16, 0, 0);
}

// ---------------------------------------------------------------------------
// x (fp32) -> bf16 workspace copy
// ---------------------------------------------------------------------------
__global__ __launch_bounds__(256)
void stage_x(const float* __restrict__ x, unsigned short* __restrict__ xb, int n) {
    for (int i = blockIdx.x * blockDim.x + threadIdx.x; i * 4 < n;
         i += gridDim.x * blockDim.x) {
        const f32x4 v = *(const f32x4*)&x[i * 4];
        unsigned short o[4];
#pragma unroll
        for (int k = 0; k < 4; k++) o[k] = f2bf(v[k]);
        *(uint64_t*)&xb[i * 4] = *(const uint64_t*)o;
    }
}

// ---------------------------------------------------------------------------
// Transpose fp32 src [R][C] -> bf16 dst [C][R]
// ---------------------------------------------------------------------------
__global__ __launch_bounds__(256)
void transpose_f32_bf16(const float* __restrict__ src,
                        unsigned short* __restrict__ dst, int R, int C) {
    __shared__ unsigned short tile[32][34];
    int bx = blockIdx.x * 32;   // col base in src
    int by = blockIdx.y * 32;   // row base in src
    int tx = threadIdx.x;       // 0..31
    int ty = threadIdx.y;       // 0..7
#pragma unroll
    for (int i = 0; i < 32; i += 8)
        tile[ty + i][tx] = f2bf(src[(size_t)(by + ty + i) * C + bx + tx]);
    __syncthreads();
#pragma unroll
    for (int i = 0; i < 32; i += 8)
        dst[(size_t)(bx + ty + i) * R + by + tx] = tile[tx][ty + i];
}

// ---------------------------------------------------------------------------
// GEMM: C[M][N] = A[M][K] * Bt[N][K]^T (+bias fp32), bf16 in, fp32 acc.
// MODE 0: QKV routing epilogue -> bf16 internal buffers (q, k, v^T)
//         q gets pre-scaled by Q_PRESCALE (softmax scale folded in)
// MODE 1: plain epilogue -> fp32 out
// Tile 128x128, BK=32, 256 threads (4 waves 2x2).
// v8: staging via global_load_lds width=16 (m97 ladder step 3, 517->874 TF):
//   per K-step, 4 wave-uniform-base async16 calls (A rows 0-63 / 64-127 and
//   B same) replace the register round-trip. LDS layout [row][32] unchanged;
//   chunk c = p*4+wave covers rows c*16..c*16+15, lane l -> row c*16 + l/4,
//   col (l&3)*8 -- matches gload_lds's linear dest = base + lane*16.
// ---------------------------------------------------------------------------
template <int MODE>
__global__ __launch_bounds__(256)
void gemm_bt(const unsigned short* __restrict__ A,
             const unsigned short* __restrict__ Bt,
             const float* __restrict__ b0,
             const float* __restrict__ b1,
             const float* __restrict__ b2,
             unsigned short* __restrict__ out0,
             unsigned short* __restrict__ out1,
             unsigned short* __restrict__ out2,
             float* __restrict__ outF,
             int K) {
    __shared__ __align__(16) unsigned short As[128 * 32];
    __shared__ __align__(16) unsigned short Bs[128 * 32];

    const int t    = threadIdx.x;
    const int wave = t >> 6;
    const int lane = t & 63;
    const int quad = lane >> 4;
    const int l16  = lane & 15;
    const int wm   = (wave >> 1) * 64;
    const int wn   = (wave & 1) * 64;
    const int rowBase = blockIdx.y * 128;
    const int colBase = blockIdx.x * 128;

    f32x4 acc[4][4];
#pragma unroll
    for (int i = 0; i < 4; i++)
#pragma unroll
        for (int j = 0; j < 4; j++)
            acc[i][j] = (f32x4){0.f, 0.f, 0.f, 0.f};

    // Staging geometry (global side, per-lane): chunk c=p*4+wave covers rows
    // c*16..c*16+15; lane l -> row c*16 + (l>>2), col (l&3)*8 shorts.
    const int lr = lane >> 2;          // 0..15
    const int lc = (lane & 3) * 8;     // 0,8,16,24
    const unsigned short* ApT = A  + (size_t)(rowBase + wave * 16 + lr) * K + lc;
    const unsigned short* BpT = Bt + (size_t)(colBase + wave * 16 + lr) * K + lc;
    const size_t rowStep = (size_t)64 * K;
    unsigned short* AsW0 = &As[wave * 512];         // rows wave*16..+15
    unsigned short* AsW1 = &As[(4 + wave) * 512];   // rows 64+wave*16..+15
    unsigned short* BsW0 = &Bs[wave * 512];
    unsigned short* BsW1 = &Bs[(4 + wave) * 512];

    for (int k0 = 0; k0 < K; k0 += 32) {
        async16(AsW0, ApT + k0);
        async16(AsW1, ApT + rowStep + k0);
        async16(BsW0, BpT + k0);
        async16(BsW1, BpT + rowStep + k0);
        __syncthreads();   // implicit vmcnt(0) drain publishes the tile

        short8 af[4], bfr[4];
#pragma unroll
        for (int i = 0; i < 4; i++)
            af[i] = *(const short8*)&As[(wm + i * 16 + l16) * 32 + quad * 8];
#pragma unroll
        for (int i = 0; i < 4; i++)
            bfr[i] = *(const short8*)&Bs[(wn + i * 16 + l16) * 32 + quad * 8];

#pragma unroll
        for (int mi = 0; mi < 4; mi++)
#pragma unroll
            for (int ni = 0; ni < 4; ni++)
                acc[mi][ni] = __builtin_amdgcn_mfma_f32_16x16x32_bf16(
                    af[mi], bfr[ni], acc[mi][ni], 0, 0, 0);
        __syncthreads();
    }

    // Epilogue. Verified C/D layout: col = lane&15, row = quad*4 + reg.
#pragma unroll
    for (int mi = 0; mi < 4; mi++) {
        const int rowT = rowBase + wm + mi * 16 + quad * 4;
#pragma unroll
        for (int ni = 0; ni < 4; ni++) {
            const int col = colBase + wn + ni * 16 + l16;
#pragma unroll
            for (int r = 0; r < 4; r++) {
                float v = acc[mi][ni][r];
                const int rr = rowT + r;
                if (MODE == 0) {
                    if (col < D_MODEL) {
                        v = (v + b0[col]) * Q_PRESCALE;   // fold softmax scale+log2e
                        out0[(size_t)rr * D_MODEL + col] = f2bf(v);
                    } else if (col < D_MODEL + KV_DIM) {
                        const int c = col - D_MODEL;
                        v += b1[c];
                        out1[(size_t)rr * KV_DIM + c] = f2bf(v);
                    } else {
                        const int c = col - (D_MODEL + KV_DIM);
                        v += b2[c];
                        const int b   = rr >> 11;       // /2048
                        const int tt  = rr & 2047;
                        const int kvh = c >> 6;
                        const int d   = c & 63;
                        out2[((size_t)((b * N_KV + kvh) * D_K + d)) * T_SEQ + tt] = f2bf(v);
                    }
                } else {
                    v += b0[col];
                    outF[(size_t)rr * D_MODEL + col] = v;   // fp32 final output
                }
            }
        }
    }
}

// ---------------------------------------------------------------------------
// Flash attention (causal, GQA). One block = (b, h, q-tile of 256 rows).
// 8 waves (512 threads); wave w owns q-rows [w*32, w*32+32). KV tiles of 64.
//
// v7 (verified, 317 us): 4-slot ring + counted vmcnt; swapped QK^T;
// in-register softmax (tree reductions); shuffle-free PV (A and B share the
// same k-permutation sigma; P stays in QK^T's C-layout, V read under sigma).
// ---------------------------------------------------------------------------
__global__ __launch_bounds__(512)
void attn_fwd(const unsigned short* __restrict__ qb,
              const unsigned short* __restrict__ kb,
              const unsigned short* __restrict__ vt,
              unsigned short* __restrict__ ob) {
    __shared__ __align__(16) unsigned short Ks[4][64 * 64];
    __shared__ __align__(16) unsigned short Vs[4][64 * 64];

    const int t    = threadIdx.x;
    const int wave = t >> 6;
    const int lane = t & 63;
    const int quad = lane >> 4;
    const int l16  = lane & 15;
    const int qt   = (int)gridDim.x - 1 - (int)blockIdx.x;  // longest blocks first
    const int h    = blockIdx.y;
    const int b    = blockIdx.z;
    const int kvh  = h >> 2;
    const int qBase = qt * 256;
    const int rowG  = b * T_SEQ;
    const size_t vtBase = (size_t)(b * N_KV + kvh) * D_K * T_SEQ;

    // Q fragments (B-operand: row = l16 -> q, cols kk*32 + quad*8)
    short8 qf[2][2];
#pragma unroll
    for (int mi = 0; mi < 2; mi++) {
        const int row = rowG + qBase + wave * 32 + mi * 16 + l16;
#pragma unroll
        for (int kk = 0; kk < 2; kk++)
            qf[mi][kk] = *(const short8*)&qb[(size_t)row * D_MODEL + h * D_K + kk * 32 + quad * 8];
    }

    f32x4 oacc[2][4];
#pragma unroll
    for (int i = 0; i < 2; i++)
#pragma unroll
        for (int j = 0; j < 4; j++)
            oacc[i][j] = (f32x4){0.f, 0.f, 0.f, 0.f};
    float m_run[2], l_run[2];
#pragma unroll
    for (int i = 0; i < 2; i++) { m_run[i] = NEG_BIG; l_run[i] = 0.f; }

    // staging geometry: thread t covers LDS row (t>>3) of 64, 16B chunk t&7.
    // Source col pre-swizzled so a swizzled read (col ^ ((row&7)<<4)) is linear.
    const int rr  = t >> 3;                          // 0..63
    const int sc8 = ((t & 7) ^ (rr & 7)) << 3;       // swizzled col, in shorts

    // EXACTLY 2 global_load_lds per stage() call (vmcnt bookkeeping relies on it)
    auto stage = [&](int bi, int sB) {
        async16(&Ks[bi][wave * 8 * 64],
                kb + (size_t)(rowG + sB + rr) * KV_DIM + kvh * D_K + sc8);
        async16(&Vs[bi][wave * 8 * 64],
                vt + vtBase + (size_t)rr * T_SEQ + sB + sc8);
    };

    const int jMax = 4 * qt + 3;   // >= 3 always

    // Prologue: fill pipeline 3 deep (6 outstanding loads per thread).
    stage(0, 0);
    stage(1, 64);
    stage(2, 128);

    for (int j = 0; j <= jMax; ++j) {
        const int rem = jMax - j;
        // Wait until tile j's loads (the oldest) are complete, keeping later
        // tiles in flight. Outstanding before wait: 6 (steady) / 4 / 2 (tail).
        if (rem >= 2)      asm volatile("s_waitcnt vmcnt(4)" ::: "memory");
        else if (rem == 1) asm volatile("s_waitcnt vmcnt(2)" ::: "memory");
        else               asm volatile("s_waitcnt vmcnt(0)" ::: "memory");
        __builtin_amdgcn_s_barrier();          // all waves' tile-j loads done
        __builtin_amdgcn_sched_barrier(0);

        // Refill: buffer (j+3)&3 was consumed at iteration j-1 (all waves
        // passed the barrier above since) -> safe to overwrite.
        if (rem >= 3) stage((j + 3) & 3, (j + 3) * 64);

        const int sRel = j * 64 - qBase;              // tile col base rel. to q rows
        const bool skip   = sRel > wave * 32 + 31;    // tile fully above diagonal
        const bool doMask = sRel + 63 > wave * 32;    // tile touches diagonal

        if (!skip) {
            const int bi = j & 3;
            const char* KsB = (const char*)&Ks[bi][0];
            const char* VsB = (const char*)&Vs[bi][0];
            const int swz   = (l16 & 7) << 4;

            // Swapped QK^T: sacc[ni][mi][r] = S[q = mi*16+l16][k = ni*16+quad*4+r]
            f32x4 sacc[4][2];
            __builtin_amdgcn_s_setprio(1);
#pragma unroll
            for (int ni = 0; ni < 4; ni++) {
                const int rowB = (ni * 16 + l16) * 128;
                const short8 kf0 = *(const short8*)(KsB + rowB + ((quad * 16) ^ swz));
                const short8 kf1 = *(const short8*)(KsB + rowB + ((64 + quad * 16) ^ swz));
#pragma unroll
                for (int mi = 0; mi < 2; mi++) {
                    f32x4 s = (f32x4){0.f, 0.f, 0.f, 0.f};
                    s = __builtin_amdgcn_mfma_f32_16x16x32_bf16(kf0, qf[mi][0], s, 0, 0, 0);
                    s = __builtin_amdgcn_mfma_f32_16x16x32_bf16(kf1, qf[mi][1], s, 0, 0, 0);
                    sacc[ni][mi] = s;
                }
            }
            __builtin_amdgcn_s_setprio(0);

            // In-register softmax (per q-row = per lane, per mi); logits already
            // scaled by log2e -> pure exp2. Tree reductions in-lane.
            uint2 packed[4][2];
#pragma unroll
            for (int mi = 0; mi < 2; mi++) {
                float v[16];
#pragma unroll
                for (int ni = 0; ni < 4; ni++)
#pragma unroll
                    for (int r = 0; r < 4; r++) {
                        float x = sacc[ni][mi][r];
                        if (doMask) {
                            const int kc = sRel + ni * 16 + quad * 4 + r;
                            const int qr = wave * 32 + mi * 16 + l16;
                            if (kc > qr) x = NEG_BIG;
                        }
                        v[ni * 4 + r] = x;
                    }
                float m8[8];
#pragma unroll
                for (int i = 0; i < 8; i++) m8[i] = fmaxf(v[i], v[i + 8]);
                float m4[4];
#pragma unroll
                for (int i = 0; i < 4; i++) m4[i] = fmaxf(m8[i], m8[i + 4]);
                float tm = fmaxf(fmaxf(m4[0], m4[1]), fmaxf(m4[2], m4[3]));
                tm = fmaxf(tm, __shfl_xor(tm, 16));
                tm = fmaxf(tm, __shfl_xor(tm, 32));

                float mref = m_run[mi];
                float mnew, alpha;
                if (__all(tm <= mref + 11.0f)) {      // defer-max (T13, log2 units)
                    mnew = mref; alpha = 1.f;
                } else {
                    mnew  = fmaxf(mref, tm);
                    alpha = e2(mref - mnew);
                    m_run[mi] = mnew;
                    // oacc rows are q = quad*4+r2; alpha lives at lane l16 = q
#pragma unroll
                    for (int r2 = 0; r2 < 4; r2++) {
                        const float aR = __shfl(alpha, (lane & 48) + quad * 4 + r2);
#pragma unroll
                        for (int di = 0; di < 4; di++) oacc[mi][di][r2] *= aR;
                    }
                }
                float p[16];
#pragma unroll
                for (int i = 0; i < 16; i++) p[i] = e2(v[i] - mnew);
                float s8[8];
#pragma unroll
                for (int i = 0; i < 8; i++) s8[i] = p[i] + p[i + 8];
                float s4[4];
#pragma unroll
                for (int i = 0; i < 4; i++) s4[i] = s8[i] + s8[i + 4];
                float rs = (s4[0] + s4[1]) + (s4[2] + s4[3]);
                rs += __shfl_xor(rs, 16);
                rs += __shfl_xor(rs, 32);
                l_run[mi] = l_run[mi] * alpha + rs;
#pragma unroll
                for (int ni = 0; ni < 4; ni++) {
                    packed[ni][mi].x = cvtpk_bf16(p[ni * 4 + 0], p[ni * 4 + 1]);
                    packed[ni][mi].y = cvtpk_bf16(p[ni * 4 + 2], p[ni * 4 + 3]);
                }
            }

            // PV, shuffle-free: A slot (quad, s=2w+b) holds
            //   P[q=l16][sigma], sigma = 32ks + 16(w>>1) + 4quad + 2(w&1) + b
            // (pa = pure per-lane repack of packed). V read under the SAME
            // sigma: slots 0-3 <- elems 32ks+4quad+0..3, slots 4-7 <- +16.
#pragma unroll
            for (int ks = 0; ks < 2; ks++) {
                short8 pa[2];
#pragma unroll
                for (int mi = 0; mi < 2; mi++) {
                    union { unsigned u[4]; short8 s; } pw;
                    pw.u[0] = packed[2 * ks][mi].x;
                    pw.u[1] = packed[2 * ks][mi].y;
                    pw.u[2] = packed[2 * ks + 1][mi].x;
                    pw.u[3] = packed[2 * ks + 1][mi].y;
                    pa[mi] = pw.s;
                }
                __builtin_amdgcn_s_setprio(1);
#pragma unroll
                for (int di = 0; di < 4; di++) {
                    const int rowB = (di * 16 + l16) * 128;
                    const uint2 lo = *(const uint2*)(VsB + rowB + ((ks * 64 + quad * 8) ^ swz));
                    const uint2 hi = *(const uint2*)(VsB + rowB + ((ks * 64 + 32 + quad * 8) ^ swz));
                    union { unsigned u[4]; short8 s; } vv;
                    vv.u[0] = lo.x; vv.u[1] = lo.y; vv.u[2] = hi.x; vv.u[3] = hi.y;
#pragma unroll
                    for (int mi = 0; mi < 2; mi++)
                        oacc[mi][di] = __builtin_amdgcn_mfma_f32_16x16x32_bf16(
                            pa[mi], vv.s, oacc[mi][di], 0, 0, 0);
                }
                __builtin_amdgcn_s_setprio(0);
            }
        }
    }

    // Epilogue: normalize and store bf16 (ob aliases qb: own slice only).
    // oacc rows are q = quad*4+r; l_run lives at lane l16 = q -> shuffle.
#pragma unroll
    for (int mi = 0; mi < 2; mi++) {
#pragma unroll
        for (int r = 0; r < 4; r++) {
            const float lr  = __shfl(l_run[mi], (lane & 48) + quad * 4 + r);
            const float inv = 1.f / lr;
            const int row = rowG + qBase + wave * 32 + mi * 16 + quad * 4 + r;
#pragma unroll
            for (int di = 0; di < 4; di++)
                ob[(size_t)row * D_MODEL + h * D_K + di * 16 + l16] =
                    f2bf(oacc[mi][di][r] * inv);
        }
    }
}

// ---------------------------------------------------------------------------
extern "C" void kernel_launch(void* const* d_in, const int* in_sizes, int n_in,
                              void* d_out, int out_size, void* d_ws, size_t ws_size,
                              hipStream_t stream) {
    const float* x  = (const float*)d_in[0];
    const float* Wq = (const float*)d_in[1];
    const float* bq = (const float*)d_in[2];
    const float* Wk = (const float*)d_in[3];
    const float* bk = (const float*)d_in[4];
    const float* Wv = (const float*)d_in[5];
    const float* bv = (const float*)d_in[6];
    const float* Wo = (const float*)d_in[7];
    const float* bo = (const float*)d_in[8];
    float* out = (float*)d_out;

    // Workspace (79,691,776 B; ws_size proven >= 79,691,824):
    //   qb   [0,        33554432)  q bf16 (8192x2048), attn out in place
    //   Wbuf [33554432, 46137344)  W1t (3072x2048 bf16), then Wot
    //   xb   [46137344, 79691776)  x as bf16
    // K and V^T (bf16, 16.8 MB) live at the head of d_out (67 MB fp32 buffer)
    // until gemm2 overwrites d_out with the final fp32 result.
    char* ws = (char*)d_ws;
    unsigned short* qb   = (unsigned short*)(ws);
    unsigned short* Wbuf = (unsigned short*)(ws + 33554432);
    unsigned short* xb   = (unsigned short*)(ws + 46137344);
    unsigned short* kb   = (unsigned short*)d_out;              // 8.4 MB
    unsigned short* vt   = (unsigned short*)d_out + 4194304;    // 8.4 MB

    stage_x<<<4096, 256, 0, stream>>>(x, xb, 16777216);

    dim3 tb(32, 8);
    transpose_f32_bf16<<<dim3(64, 64), tb, 0, stream>>>(Wq, Wbuf, 2048, 2048);
    transpose_f32_bf16<<<dim3(16, 64), tb, 0, stream>>>(Wk, Wbuf + 2048 * 2048, 2048, 512);
    transpose_f32_bf16<<<dim3(16, 64), tb, 0, stream>>>(Wv, Wbuf + 2560 * 2048, 2048, 512);

    gemm_bt<0><<<dim3(N1 / 128, M_TOT / 128), 256, 0, stream>>>(
        xb, Wbuf, bq, bk, bv, qb, kb, vt, nullptr, D_MODEL);

    // W1t no longer needed; stage Wo^T into the same buffer (stream-ordered).
    transpose_f32_bf16<<<dim3(64, 64), tb, 0, stream>>>(Wo, Wbuf, 2048, 2048);

    attn_fwd<<<dim3(T_SEQ / 256, N_HEADS, B_SZ), 512, 0, stream>>>(qb, kb, vt, qb);

    gemm_bt<1><<<dim3(D_MODEL / 128, M_TOT / 128), 256, 0, stream>>>(
        qb, Wbuf, bo, nullptr, nullptr, nullptr, nullptr, nullptr, out, D_MODEL);
}

// Round 8
// 698.844 us; speedup vs baseline: 1.0507x; 1.0507x over previous
//
#include <hip/hip_runtime.h>
#include <cstdint>
#include <cstddef>

typedef __attribute__((ext_vector_type(8))) short short8;
typedef __attribute__((ext_vector_type(4))) float f32x4;

#define D_MODEL 2048
#define KV_DIM  512
#define N_HEADS 32
#define N_KV    8
#define D_K     64
#define B_SZ    4
#define T_SEQ   2048
#define M_TOT   (B_SZ * T_SEQ)        /* 8192 */
#define N1      (D_MODEL + 2 * KV_DIM) /* 3072 */
#define NEG_BIG (-1e30f)
/* 1/sqrt(64) * log2(e): folded into q at GEMM epilogue so softmax is pure exp2 */
#define Q_PRESCALE 0.18033688011112042f

__device__ __forceinline__ unsigned short f2bf(float f) {
    union { float f; unsigned int i; } c; c.f = f;
    unsigned int u = c.i;
    u += 0x7FFFu + ((u >> 16) & 1u);   // RNE
    return (unsigned short)(u >> 16);
}

// v_cvt_pk_bf16_f32: lo -> bits[15:0], hi -> bits[31:16] (no builtin on gfx950)
__device__ __forceinline__ unsigned int cvtpk_bf16(float lo, float hi) {
    unsigned int r;
    asm("v_cvt_pk_bf16_f32 %0, %1, %2" : "=v"(r) : "v"(lo), "v"(hi));
    return r;
}

// 2^x, single trans op (logits are pre-scaled by log2e)
__device__ __forceinline__ float e2(float x) {
    float r;
    asm("v_exp_f32 %0, %1" : "=v"(r) : "v"(x));
    return r;
}

// async global->LDS, 16B per lane; LDS dest = wave-uniform base + lane*16
__device__ __forceinline__ void async16(unsigned short* lds, const unsigned short* g) {
    __builtin_amdgcn_global_load_lds(
        (const __attribute__((address_space(1))) unsigned int*)g,
        (__attribute__((address_space(3))) unsigned int*)lds, 16, 0, 0);
}

// ---------------------------------------------------------------------------
// x (fp32) -> bf16 workspace copy
// ---------------------------------------------------------------------------
__global__ __launch_bounds__(256)
void stage_x(const float* __restrict__ x, unsigned short* __restrict__ xb, int n) {
    for (int i = blockIdx.x * blockDim.x + threadIdx.x; i * 4 < n;
         i += gridDim.x * blockDim.x) {
        const f32x4 v = *(const f32x4*)&x[i * 4];
        unsigned short o[4];
#pragma unroll
        for (int k = 0; k < 4; k++) o[k] = f2bf(v[k]);
        *(uint64_t*)&xb[i * 4] = *(const uint64_t*)o;
    }
}

// ---------------------------------------------------------------------------
// Transpose fp32 src [R][C] -> bf16 dst [C][R]
// ---------------------------------------------------------------------------
__global__ __launch_bounds__(256)
void transpose_f32_bf16(const float* __restrict__ src,
                        unsigned short* __restrict__ dst, int R, int C) {
    __shared__ unsigned short tile[32][34];
    int bx = blockIdx.x * 32;   // col base in src
    int by = blockIdx.y * 32;   // row base in src
    int tx = threadIdx.x;       // 0..31
    int ty = threadIdx.y;       // 0..7
#pragma unroll
    for (int i = 0; i < 32; i += 8)
        tile[ty + i][tx] = f2bf(src[(size_t)(by + ty + i) * C + bx + tx]);
    __syncthreads();
#pragma unroll
    for (int i = 0; i < 32; i += 8)
        dst[(size_t)(bx + ty + i) * R + by + tx] = tile[tx][ty + i];
}

// ---------------------------------------------------------------------------
// GEMM: C[M][N] = A[M][K] * Bt[N][K]^T (+bias fp32), bf16 in, fp32 acc.
// MODE 0: QKV routing epilogue -> bf16 internal buffers (q, k, v^T)
//         q gets pre-scaled by Q_PRESCALE (softmax scale folded in)
// MODE 1: plain epilogue -> fp32 out
// Tile 128x128, BK=32, 256 threads (4 waves 2x2). (m92-verified pattern;
// register staging -- round-7's gload_lds variant measured neutral, reverted)
// ---------------------------------------------------------------------------
template <int MODE>
__global__ __launch_bounds__(256)
void gemm_bt(const unsigned short* __restrict__ A,
             const unsigned short* __restrict__ Bt,
             const float* __restrict__ b0,
             const float* __restrict__ b1,
             const float* __restrict__ b2,
             unsigned short* __restrict__ out0,
             unsigned short* __restrict__ out1,
             unsigned short* __restrict__ out2,
             float* __restrict__ outF,
             int K) {
    __shared__ __align__(16) unsigned short As[128 * 32];
    __shared__ __align__(16) unsigned short Bs[128 * 32];

    const int t    = threadIdx.x;
    const int wave = t >> 6;
    const int lane = t & 63;
    const int quad = lane >> 4;
    const int l16  = lane & 15;
    const int wm   = (wave >> 1) * 64;
    const int wn   = (wave & 1) * 64;
    const int rowBase = blockIdx.y * 128;
    const int colBase = blockIdx.x * 128;

    f32x4 acc[4][4];
#pragma unroll
    for (int i = 0; i < 4; i++)
#pragma unroll
        for (int j = 0; j < 4; j++)
            acc[i][j] = (f32x4){0.f, 0.f, 0.f, 0.f};

    const int r0  = t >> 2;          // 0..63
    const int off = (t & 3) * 8;     // 0,8,16,24
    const unsigned short* Ap = A  + (size_t)(rowBase + r0) * K + off;
    const unsigned short* Bp = Bt + (size_t)(colBase + r0) * K + off;
    const size_t rowStep = (size_t)64 * K;

    for (int k0 = 0; k0 < K; k0 += 32) {
        *(short8*)&As[t * 8]         = *(const short8*)(Ap + k0);
        *(short8*)&As[(t + 256) * 8] = *(const short8*)(Ap + rowStep + k0);
        *(short8*)&Bs[t * 8]         = *(const short8*)(Bp + k0);
        *(short8*)&Bs[(t + 256) * 8] = *(const short8*)(Bp + rowStep + k0);
        __syncthreads();

        short8 af[4], bfr[4];
#pragma unroll
        for (int i = 0; i < 4; i++)
            af[i] = *(const short8*)&As[(wm + i * 16 + l16) * 32 + quad * 8];
#pragma unroll
        for (int i = 0; i < 4; i++)
            bfr[i] = *(const short8*)&Bs[(wn + i * 16 + l16) * 32 + quad * 8];

#pragma unroll
        for (int mi = 0; mi < 4; mi++)
#pragma unroll
            for (int ni = 0; ni < 4; ni++)
                acc[mi][ni] = __builtin_amdgcn_mfma_f32_16x16x32_bf16(
                    af[mi], bfr[ni], acc[mi][ni], 0, 0, 0);
        __syncthreads();
    }

    // Epilogue. Verified C/D layout: col = lane&15, row = quad*4 + reg.
#pragma unroll
    for (int mi = 0; mi < 4; mi++) {
        const int rowT = rowBase + wm + mi * 16 + quad * 4;
#pragma unroll
        for (int ni = 0; ni < 4; ni++) {
            const int col = colBase + wn + ni * 16 + l16;
#pragma unroll
            for (int r = 0; r < 4; r++) {
                float v = acc[mi][ni][r];
                const int rr = rowT + r;
                if (MODE == 0) {
                    if (col < D_MODEL) {
                        v = (v + b0[col]) * Q_PRESCALE;   // fold softmax scale+log2e
                        out0[(size_t)rr * D_MODEL + col] = f2bf(v);
                    } else if (col < D_MODEL + KV_DIM) {
                        const int c = col - D_MODEL;
                        v += b1[c];
                        out1[(size_t)rr * KV_DIM + c] = f2bf(v);
                    } else {
                        const int c = col - (D_MODEL + KV_DIM);
                        v += b2[c];
                        const int b   = rr >> 11;       // /2048
                        const int tt  = rr & 2047;
                        const int kvh = c >> 6;
                        const int d   = c & 63;
                        out2[((size_t)((b * N_KV + kvh) * D_K + d)) * T_SEQ + tt] = f2bf(v);
                    }
                } else {
                    v += b0[col];
                    outF[(size_t)rr * D_MODEL + col] = v;   // fp32 final output
                }
            }
        }
    }
}

// ---------------------------------------------------------------------------
// Flash attention (causal, GQA). One block = (b, h, q-tile of 256 rows).
// 8 waves (512 threads); wave w owns q-rows [w*32, w*32+32). KV tiles of 64.
//
// v9 = v7 (verified, 317us) + ONE mechanism: shuffle-free steady-path softmax.
//  - Defer-max check uses each lane's PARTIAL 16-elem max: __all() spans all
//    quads, so __all(partial<=m+THR) is exactly equivalent to the row-max
//    check. The cross-quad max reduce moves into the rare rescale branch.
//  - l_run is kept as per-lane PARTIAL sums through the loop (alpha is
//    row-uniform so the recurrence commutes with the quad reduction);
//    the 2-shuffle quad reduce runs ONCE in the epilogue.
//  => zero ds_bpermute in the steady per-tile path (was 4, ~480cy of chain).
// ---------------------------------------------------------------------------
__global__ __launch_bounds__(512)
void attn_fwd(const unsigned short* __restrict__ qb,
              const unsigned short* __restrict__ kb,
              const unsigned short* __restrict__ vt,
              unsigned short* __restrict__ ob) {
    __shared__ __align__(16) unsigned short Ks[4][64 * 64];
    __shared__ __align__(16) unsigned short Vs[4][64 * 64];

    const int t    = threadIdx.x;
    const int wave = t >> 6;
    const int lane = t & 63;
    const int quad = lane >> 4;
    const int l16  = lane & 15;
    const int qt   = (int)gridDim.x - 1 - (int)blockIdx.x;  // longest blocks first
    const int h    = blockIdx.y;
    const int b    = blockIdx.z;
    const int kvh  = h >> 2;
    const int qBase = qt * 256;
    const int rowG  = b * T_SEQ;
    const size_t vtBase = (size_t)(b * N_KV + kvh) * D_K * T_SEQ;

    // Q fragments (B-operand: row = l16 -> q, cols kk*32 + quad*8)
    short8 qf[2][2];
#pragma unroll
    for (int mi = 0; mi < 2; mi++) {
        const int row = rowG + qBase + wave * 32 + mi * 16 + l16;
#pragma unroll
        for (int kk = 0; kk < 2; kk++)
            qf[mi][kk] = *(const short8*)&qb[(size_t)row * D_MODEL + h * D_K + kk * 32 + quad * 8];
    }

    f32x4 oacc[2][4];
#pragma unroll
    for (int i = 0; i < 2; i++)
#pragma unroll
        for (int j = 0; j < 4; j++)
            oacc[i][j] = (f32x4){0.f, 0.f, 0.f, 0.f};
    float m_run[2], l_run[2];   // m_run: row max (row-uniform); l_run: PARTIAL sums
#pragma unroll
    for (int i = 0; i < 2; i++) { m_run[i] = NEG_BIG; l_run[i] = 0.f; }

    // staging geometry: thread t covers LDS row (t>>3) of 64, 16B chunk t&7.
    // Source col pre-swizzled so a swizzled read (col ^ ((row&7)<<4)) is linear.
    const int rr  = t >> 3;                          // 0..63
    const int sc8 = ((t & 7) ^ (rr & 7)) << 3;       // swizzled col, in shorts

    // EXACTLY 2 global_load_lds per stage() call (vmcnt bookkeeping relies on it)
    auto stage = [&](int bi, int sB) {
        async16(&Ks[bi][wave * 8 * 64],
                kb + (size_t)(rowG + sB + rr) * KV_DIM + kvh * D_K + sc8);
        async16(&Vs[bi][wave * 8 * 64],
                vt + vtBase + (size_t)rr * T_SEQ + sB + sc8);
    };

    const int jMax = 4 * qt + 3;   // >= 3 always

    // Prologue: fill pipeline 3 deep (6 outstanding loads per thread).
    stage(0, 0);
    stage(1, 64);
    stage(2, 128);

    for (int j = 0; j <= jMax; ++j) {
        const int rem = jMax - j;
        // Wait until tile j's loads (the oldest) are complete, keeping later
        // tiles in flight. Outstanding before wait: 6 (steady) / 4 / 2 (tail).
        if (rem >= 2)      asm volatile("s_waitcnt vmcnt(4)" ::: "memory");
        else if (rem == 1) asm volatile("s_waitcnt vmcnt(2)" ::: "memory");
        else               asm volatile("s_waitcnt vmcnt(0)" ::: "memory");
        __builtin_amdgcn_s_barrier();          // all waves' tile-j loads done
        __builtin_amdgcn_sched_barrier(0);

        // Refill: buffer (j+3)&3 was consumed at iteration j-1 (all waves
        // passed the barrier above since) -> safe to overwrite.
        if (rem >= 3) stage((j + 3) & 3, (j + 3) * 64);

        const int sRel = j * 64 - qBase;              // tile col base rel. to q rows
        const bool skip   = sRel > wave * 32 + 31;    // tile fully above diagonal
        const bool doMask = sRel + 63 > wave * 32;    // tile touches diagonal

        if (!skip) {
            const int bi = j & 3;
            const char* KsB = (const char*)&Ks[bi][0];
            const char* VsB = (const char*)&Vs[bi][0];
            const int swz   = (l16 & 7) << 4;

            // Swapped QK^T: sacc[ni][mi][r] = S[q = mi*16+l16][k = ni*16+quad*4+r]
            f32x4 sacc[4][2];
            __builtin_amdgcn_s_setprio(1);
#pragma unroll
            for (int ni = 0; ni < 4; ni++) {
                const int rowB = (ni * 16 + l16) * 128;
                const short8 kf0 = *(const short8*)(KsB + rowB + ((quad * 16) ^ swz));
                const short8 kf1 = *(const short8*)(KsB + rowB + ((64 + quad * 16) ^ swz));
#pragma unroll
                for (int mi = 0; mi < 2; mi++) {
                    f32x4 s = (f32x4){0.f, 0.f, 0.f, 0.f};
                    s = __builtin_amdgcn_mfma_f32_16x16x32_bf16(kf0, qf[mi][0], s, 0, 0, 0);
                    s = __builtin_amdgcn_mfma_f32_16x16x32_bf16(kf1, qf[mi][1], s, 0, 0, 0);
                    sacc[ni][mi] = s;
                }
            }
            __builtin_amdgcn_s_setprio(0);

            // In-register softmax; logits pre-scaled by log2e -> pure exp2.
            // Steady path is fully in-lane (no cross-lane ops).
            uint2 packed[4][2];
#pragma unroll
            for (int mi = 0; mi < 2; mi++) {
                float v[16];
#pragma unroll
                for (int ni = 0; ni < 4; ni++)
#pragma unroll
                    for (int r = 0; r < 4; r++) {
                        float x = sacc[ni][mi][r];
                        if (doMask) {
                            const int kc = sRel + ni * 16 + quad * 4 + r;
                            const int qr = wave * 32 + mi * 16 + l16;
                            if (kc > qr) x = NEG_BIG;
                        }
                        v[ni * 4 + r] = x;
                    }
                // per-lane partial max (16 elems, tree)
                float m8[8];
#pragma unroll
                for (int i = 0; i < 8; i++) m8[i] = fmaxf(v[i], v[i + 8]);
                float m4[4];
#pragma unroll
                for (int i = 0; i < 4; i++) m4[i] = fmaxf(m8[i], m8[i + 4]);
                float tmp = fmaxf(fmaxf(m4[0], m4[1]), fmaxf(m4[2], m4[3]));

                float mref = m_run[mi];
                float mnew, alpha;
                // __all over 64 lanes covers all quads -> equivalent to the
                // row-max check; cross-quad reduce only in the rare branch.
                if (__all(tmp <= mref + 11.0f)) {     // defer-max (T13, log2 units)
                    mnew = mref; alpha = 1.f;
                } else {
                    float tm = tmp;
                    tm = fmaxf(tm, __shfl_xor(tm, 16));
                    tm = fmaxf(tm, __shfl_xor(tm, 32));
                    mnew  = fmaxf(mref, tm);
                    alpha = e2(mref - mnew);
                    m_run[mi] = mnew;
                    // oacc rows are q = quad*4+r2; alpha lives at lane l16 = q
#pragma unroll
                    for (int r2 = 0; r2 < 4; r2++) {
                        const float aR = __shfl(alpha, (lane & 48) + quad * 4 + r2);
#pragma unroll
                        for (int di = 0; di < 4; di++) oacc[mi][di][r2] *= aR;
                    }
                }
                float p[16];
#pragma unroll
                for (int i = 0; i < 16; i++) p[i] = e2(v[i] - mnew);
                float s8[8];
#pragma unroll
                for (int i = 0; i < 8; i++) s8[i] = p[i] + p[i + 8];
                float s4[4];
#pragma unroll
                for (int i = 0; i < 4; i++) s4[i] = s8[i] + s8[i + 4];
                const float rs = (s4[0] + s4[1]) + (s4[2] + s4[3]);
                l_run[mi] = l_run[mi] * alpha + rs;   // per-lane PARTIAL sum
#pragma unroll
                for (int ni = 0; ni < 4; ni++) {
                    packed[ni][mi].x = cvtpk_bf16(p[ni * 4 + 0], p[ni * 4 + 1]);
                    packed[ni][mi].y = cvtpk_bf16(p[ni * 4 + 2], p[ni * 4 + 3]);
                }
            }

            // PV, shuffle-free: A slot (quad, s=2w+b) holds
            //   P[q=l16][sigma], sigma = 32ks + 16(w>>1) + 4quad + 2(w&1) + b
            // (pa = pure per-lane repack of packed). V read under the SAME
            // sigma: slots 0-3 <- elems 32ks+4quad+0..3, slots 4-7 <- +16.
#pragma unroll
            for (int ks = 0; ks < 2; ks++) {
                short8 pa[2];
#pragma unroll
                for (int mi = 0; mi < 2; mi++) {
                    union { unsigned u[4]; short8 s; } pw;
                    pw.u[0] = packed[2 * ks][mi].x;
                    pw.u[1] = packed[2 * ks][mi].y;
                    pw.u[2] = packed[2 * ks + 1][mi].x;
                    pw.u[3] = packed[2 * ks + 1][mi].y;
                    pa[mi] = pw.s;
                }
                __builtin_amdgcn_s_setprio(1);
#pragma unroll
                for (int di = 0; di < 4; di++) {
                    const int rowB = (di * 16 + l16) * 128;
                    const uint2 lo = *(const uint2*)(VsB + rowB + ((ks * 64 + quad * 8) ^ swz));
                    const uint2 hi = *(const uint2*)(VsB + rowB + ((ks * 64 + 32 + quad * 8) ^ swz));
                    union { unsigned u[4]; short8 s; } vv;
                    vv.u[0] = lo.x; vv.u[1] = lo.y; vv.u[2] = hi.x; vv.u[3] = hi.y;
#pragma unroll
                    for (int mi = 0; mi < 2; mi++)
                        oacc[mi][di] = __builtin_amdgcn_mfma_f32_16x16x32_bf16(
                            pa[mi], vv.s, oacc[mi][di], 0, 0, 0);
                }
                __builtin_amdgcn_s_setprio(0);
            }
        }
    }

    // Epilogue: reduce l_run partials across quads ONCE, then normalize+store.
    // oacc rows are q = quad*4+r; l_run lives at lane l16 = q -> shuffle.
#pragma unroll
    for (int mi = 0; mi < 2; mi++) {
        l_run[mi] += __shfl_xor(l_run[mi], 16);
        l_run[mi] += __shfl_xor(l_run[mi], 32);
#pragma unroll
        for (int r = 0; r < 4; r++) {
            const float lr  = __shfl(l_run[mi], (lane & 48) + quad * 4 + r);
            const float inv = 1.f / lr;
            const int row = rowG + qBase + wave * 32 + mi * 16 + quad * 4 + r;
#pragma unroll
            for (int di = 0; di < 4; di++)
                ob[(size_t)row * D_MODEL + h * D_K + di * 16 + l16] =
                    f2bf(oacc[mi][di][r] * inv);
        }
    }
}

// ---------------------------------------------------------------------------
extern "C" void kernel_launch(void* const* d_in, const int* in_sizes, int n_in,
                              void* d_out, int out_size, void* d_ws, size_t ws_size,
                              hipStream_t stream) {
    const float* x  = (const float*)d_in[0];
    const float* Wq = (const float*)d_in[1];
    const float* bq = (const float*)d_in[2];
    const float* Wk = (const float*)d_in[3];
    const float* bk = (const float*)d_in[4];
    const float* Wv = (const float*)d_in[5];
    const float* bv = (const float*)d_in[6];
    const float* Wo = (const float*)d_in[7];
    const float* bo = (const float*)d_in[8];
    float* out = (float*)d_out;

    // Workspace (79,691,776 B; ws_size proven >= 79,691,824):
    //   qb   [0,        33554432)  q bf16 (8192x2048), attn out in place
    //   Wbuf [33554432, 46137344)  W1t (3072x2048 bf16), then Wot
    //   xb   [46137344, 79691776)  x as bf16
    // K and V^T (bf16, 16.8 MB) live at the head of d_out (67 MB fp32 buffer)
    // until gemm2 overwrites d_out with the final fp32 result.
    char* ws = (char*)d_ws;
    unsigned short* qb   = (unsigned short*)(ws);
    unsigned short* Wbuf = (unsigned short*)(ws + 33554432);
    unsigned short* xb   = (unsigned short*)(ws + 46137344);
    unsigned short* kb   = (unsigned short*)d_out;              // 8.4 MB
    unsigned short* vt   = (unsigned short*)d_out + 4194304;    // 8.4 MB

    stage_x<<<4096, 256, 0, stream>>>(x, xb, 16777216);

    dim3 tb(32, 8);
    transpose_f32_bf16<<<dim3(64, 64), tb, 0, stream>>>(Wq, Wbuf, 2048, 2048);
    transpose_f32_bf16<<<dim3(16, 64), tb, 0, stream>>>(Wk, Wbuf + 2048 * 2048, 2048, 512);
    transpose_f32_bf16<<<dim3(16, 64), tb, 0, stream>>>(Wv, Wbuf + 2560 * 2048, 2048, 512);

    gemm_bt<0><<<dim3(N1 / 128, M_TOT / 128), 256, 0, stream>>>(
        xb, Wbuf, bq, bk, bv, qb, kb, vt, nullptr, D_MODEL);

    // W1t no longer needed; stage Wo^T into the same buffer (stream-ordered).
    transpose_f32_bf16<<<dim3(64, 64), tb, 0, stream>>>(Wo, Wbuf, 2048, 2048);

    attn_fwd<<<dim3(T_SEQ / 256, N_HEADS, B_SZ), 512, 0, stream>>>(qb, kb, vt, qb);

    gemm_bt<1><<<dim3(D_MODEL / 128, M_TOT / 128), 256, 0, stream>>>(
        qb, Wbuf, bo, nullptr, nullptr, nullptr, nullptr, nullptr, out, D_MODEL);
}